// Round 11
// baseline (76.965 us; speedup 1.0000x reference)
//
#include <hip/hip_runtime.h>

#define BB 32
#define CC 3
#define HH 128
#define WW 128
#define NN 1024
#define KK (CC*HH*WW)        // 49152
#define NROWS (CC*HH)        // 384
#define KSR NROWS            // 384 split-K groups (1 row each)
#define BH 16                // batches per block
#define NSL 512              // n per block (2 n-halves)
#define WCH 4                // w-columns per register chunk
#define NCH (WW/WCH)         // 32 chunks per row
#define SG 8                 // s-groups in reduce stage 1
#define STEP (1.0f/127.0f)

// ---- per-neuron normalization scale: scale[n] = sqrt(H*W/(Sx*Sy)) ----
__global__ void scale_kernel(const float* __restrict__ mu_x,
                             const float* __restrict__ mu_y,
                             const float* __restrict__ sigma_x,
                             const float* __restrict__ sigma_y,
                             float* __restrict__ scale) {
    int n = blockIdx.x * blockDim.x + threadIdx.x;
    if (n >= NN) return;
    float mux = mu_x[n], muy = mu_y[n];
    float isx = 1.0f / sigma_x[n], isy = 1.0f / sigma_y[n];
    float Sx = 0.f, Sy = 0.f;
    for (int i = 0; i < WW; ++i) {
        float dx = (i * STEP - mux) * isx;
        Sx += __expf(-dx * dx);
        float dy = (i * STEP - muy) * isy;
        Sy += __expf(-dy * dy);
    }
    scale[n] = sqrtf((float)(HH * WW) / (Sx * Sy));
}

// ---- transpose x[B,K] -> xT[K,B] (proven R1 kernel) ----
__global__ void xpose_kernel(const float* __restrict__ x, float* __restrict__ xT) {
    __shared__ float tile[64][BB + 1];
    int k0 = blockIdx.x * 64;
    int lane = threadIdx.x & 63;   // k within tile
    int bgrp = threadIdx.x >> 6;   // 0..3
#pragma unroll
    for (int i = 0; i < 8; ++i) {
        int b = bgrp * 8 + i;
        tile[lane][b] = x[(size_t)b * KK + k0 + lane];
    }
    __syncthreads();
    int b = threadIdx.x & 31;
    int kk0 = threadIdx.x >> 5;    // 0..7
#pragma unroll
    for (int i = 0; i < 8; ++i) {
        int kk = i * 8 + kk0;
        xT[(size_t)(k0 + kk) * BB + b] = tile[kk][b];
    }
}

// ---- main v7: zero-LDS register pipeline, n-split for 2x occupancy ----
// block = (row g, b-half, n-half); thread owns 2 consecutive n, 16 batches.
// Grid 1536 blocks -> 6 blocks/CU -> ~24 waves/CU (double R8's TLP).
__global__ __launch_bounds__(256) void main_pipe(
    const float* __restrict__ weights,
    const float* __restrict__ xT,
    const float* __restrict__ scale,
    const float* __restrict__ mu_x, const float* __restrict__ mu_y,
    const float* __restrict__ sigma_x, const float* __restrict__ sigma_y,
    float* __restrict__ part)
{
    const int tid = threadIdx.x;

    // XCD swizzle: the 4 siblings of a row (2 b-half x 2 n-half) -> same XCD.
    const int d    = blockIdx.x;             // 0..1535
    const int xcd  = d & 7;
    const int slot = d >> 3;                 // 0..191
    const int g    = xcd * (KSR / 8) + (slot >> 2);   // 0..383
    const int sib  = slot & 3;
    const int b0   = (sib & 1) * BH;
    const int nh   = sib >> 1;               // n-half 0/1
    const int r    = g;
    const int h    = r & (HH - 1);
    const int np   = nh * 256 + tid;         // float2 index: n = 2*np

    const float2 mux2 = ((const float2*)mu_x)[np];
    const float2 sx2  = ((const float2*)sigma_x)[np];
    const float2 muy2 = ((const float2*)mu_y)[np];
    const float2 sy2  = ((const float2*)sigma_y)[np];
    const float2 sc2  = ((const float2*)scale)[np];

    float mux[2] = {mux2.x, mux2.y};
    float ax[2], axs[2], Bf[2], gyrow[2];
    ax[0] = -0.5f/(sx2.x*sx2.x); ax[1] = -0.5f/(sx2.y*sx2.y);
    axs[0] = ax[0]*STEP;         axs[1] = ax[1]*STEP;
    Bf[0] = __expf(2.f*axs[0]*STEP); Bf[1] = __expf(2.f*axs[1]*STEP);
    {   // gy[h]*scale inline
        const float hp = h * STEP;
        float ayc, dd;
        ayc = -0.5f/(sy2.x*sy2.x); dd = hp-muy2.x; gyrow[0] = __expf(ayc*dd*dd)*sc2.x;
        ayc = -0.5f/(sy2.y*sy2.y); dd = hp-muy2.y; gyrow[1] = __expf(ayc*dd*dd)*sc2.y;
    }

    const float* wbase = weights + (size_t)r * WW * NN + np * 2;
    const float4* xr4  = (const float4*)xT + (size_t)r * (WW * BB / 4) + (b0 >> 2);
    // per w: xr4[w*8 + q], q = 0..3 (16 batches, block-uniform address)

    float2 wR[2][4];                          // double-buffered weight pairs
#define WLOAD(BUF, C)                                                   \
    {                                                                   \
        _Pragma("unroll")                                               \
        for (int i = 0; i < 4; ++i)                                     \
            wR[BUF][i] = *(const float2*)(wbase + (size_t)((C)*WCH + i) * NN); \
    }

    float2 acc[BH];
#pragma unroll
    for (int b = 0; b < BH; ++b) acc[b] = make_float2(0.f, 0.f);

    float g2[2], r2[2];
    auto resync = [&](int w0) {              // fresh exps, span <= 16 w
        const float w0s = (float)w0 * STEP;
#pragma unroll
        for (int j = 0; j < 2; ++j) {
            const float dd = w0s - mux[j];
            g2[j] = __expf(ax[j] * dd * dd) * gyrow[j];
            r2[j] = __expf(axs[j] * (2.f * dd + STEP));
        }
    };

#define FMAQ(XC, B)                                                     \
    {                                                                   \
        acc[B].x = fmaf(XC, t0, acc[B].x);                              \
        acc[B].y = fmaf(XC, t1, acc[B].y);                              \
    }

#define CHUNK(BUF, C)                                                   \
    {                                                                   \
        if (((C) & 3) == 0) resync((C) * WCH);                          \
        _Pragma("unroll")                                               \
        for (int i = 0; i < 4; ++i) {                                   \
            const int w = (C) * WCH + i;                                \
            const float4 xq0 = xr4[w*8 + 0];                            \
            const float4 xq1 = xr4[w*8 + 1];                            \
            const float4 xq2 = xr4[w*8 + 2];                            \
            const float4 xq3 = xr4[w*8 + 3];                            \
            const float t0 = g2[0] * wR[BUF][i].x;                      \
            const float t1 = g2[1] * wR[BUF][i].y;                      \
            FMAQ(xq0.x,  0) FMAQ(xq0.y,  1) FMAQ(xq0.z,  2) FMAQ(xq0.w,  3) \
            FMAQ(xq1.x,  4) FMAQ(xq1.y,  5) FMAQ(xq1.z,  6) FMAQ(xq1.w,  7) \
            FMAQ(xq2.x,  8) FMAQ(xq2.y,  9) FMAQ(xq2.z, 10) FMAQ(xq2.w, 11) \
            FMAQ(xq3.x, 12) FMAQ(xq3.y, 13) FMAQ(xq3.z, 14) FMAQ(xq3.w, 15) \
            g2[0] *= r2[0]; g2[1] *= r2[1];                             \
            r2[0] *= Bf[0]; r2[1] *= Bf[1];                             \
        }                                                               \
    }

    WLOAD(0, 0);
    for (int c = 0; c < NCH; c += 2) {
        WLOAD(1, c + 1);                     // prefetch next weight chunk
        CHUNK(0, c);                         // compute current
        if (c + 2 < NCH) WLOAD(0, c + 2);
        CHUNK(1, c + 1);
    }
#undef CHUNK
#undef FMAQ
#undef WLOAD

    // coalesced float2 stores into this block's private partial slice
    float* pp = part + ((size_t)g * BB + b0) * NN + np * 2;
#pragma unroll
    for (int b = 0; b < BH; ++b)
        *(float2*)(pp + (size_t)b * NN) = acc[b];
}

// ---- reduce stage 1: part2[sg][cq] = sum over 48 s of part[s][cq] ----
__global__ __launch_bounds__(256) void reduce1_kernel(const float* __restrict__ part,
                                                      float* __restrict__ part2) {
    const int sg = blockIdx.x >> 5;                       // 0..7
    const int cq = (blockIdx.x & 31) * 256 + threadIdx.x; // cell-quads
    const int s0 = sg * (KSR / SG);
    float4 a = make_float4(0.f, 0.f, 0.f, 0.f);
#pragma unroll 4
    for (int s = 0; s < KSR / SG; ++s) {
        const float4 v = *(const float4*)(part + (size_t)(s0 + s) * (BB * NN) + cq * 4);
        a.x += v.x; a.y += v.y; a.z += v.z; a.w += v.w;
    }
    *(float4*)(part2 + ((size_t)sg * (BB * NN) + cq * 4)) = a;
}

// ---- reduce stage 2: out[cq] = sum over 8 s-groups ----
__global__ __launch_bounds__(256) void reduce2_kernel(const float* __restrict__ part2,
                                                      float* __restrict__ out) {
    const int cq = blockIdx.x * 256 + threadIdx.x;
    float4 a = make_float4(0.f, 0.f, 0.f, 0.f);
#pragma unroll
    for (int sgi = 0; sgi < SG; ++sgi) {
        const float4 v = *(const float4*)(part2 + (size_t)sgi * (BB * NN) + cq * 4);
        a.x += v.x; a.y += v.y; a.z += v.z; a.w += v.w;
    }
    *(float4*)(out + cq * 4) = a;
}

// ---- fallback (atomic, self-contained) — proven R3 structure ----
__global__ __launch_bounds__(256) void main_fallback(
    const float* __restrict__ weights,
    const float* __restrict__ x,
    const float* __restrict__ mu_x, const float* __restrict__ mu_y,
    const float* __restrict__ sigma_x, const float* __restrict__ sigma_y,
    float* __restrict__ dst)
{
    __shared__ float tile[2][WW][8];
    const int tid = threadIdx.x;
    const int g   = blockIdx.x;
    const int b0  = blockIdx.y * 8;
    const int r0  = g * 2;

    {
        const int b = tid & 7;
        const int c = tid >> 3;
        const float* xp = x + (size_t)(b0 + b) * KK + (size_t)r0 * WW + c * 8;
        const float4 v0 = ((const float4*)xp)[0];
        const float4 v1 = ((const float4*)xp)[1];
        const int row = (c * 8) >> 7;
        const int w   = (c * 8) & (WW - 1);
        tile[row][w+0][b] = v0.x; tile[row][w+1][b] = v0.y;
        tile[row][w+2][b] = v0.z; tile[row][w+3][b] = v0.w;
        tile[row][w+4][b] = v1.x; tile[row][w+5][b] = v1.y;
        tile[row][w+6][b] = v1.z; tile[row][w+7][b] = v1.w;
    }

    float4 mux4 = ((const float4*)mu_x)[tid];
    float4 muy4 = ((const float4*)mu_y)[tid];
    float4 sx4  = ((const float4*)sigma_x)[tid];
    float4 sy4  = ((const float4*)sigma_y)[tid];
    float4 ax4, ay4, sc4;
    ax4.x=-0.5f/(sx4.x*sx4.x); ax4.y=-0.5f/(sx4.y*sx4.y);
    ax4.z=-0.5f/(sx4.z*sx4.z); ax4.w=-0.5f/(sx4.w*sx4.w);
    ay4.x=-0.5f/(sy4.x*sy4.x); ay4.y=-0.5f/(sy4.y*sy4.y);
    ay4.z=-0.5f/(sy4.z*sy4.z); ay4.w=-0.5f/(sy4.w*sy4.w);
    {
        float Sx[4]={0,0,0,0}, Sy[4]={0,0,0,0};
        for (int i = 0; i < WW; ++i) {
            float pp = i * STEP, dd;
            dd=pp-mux4.x; Sx[0]+=__expf(2.f*ax4.x*dd*dd);
            dd=pp-mux4.y; Sx[1]+=__expf(2.f*ax4.y*dd*dd);
            dd=pp-mux4.z; Sx[2]+=__expf(2.f*ax4.z*dd*dd);
            dd=pp-mux4.w; Sx[3]+=__expf(2.f*ax4.w*dd*dd);
            dd=pp-muy4.x; Sy[0]+=__expf(2.f*ay4.x*dd*dd);
            dd=pp-muy4.y; Sy[1]+=__expf(2.f*ay4.y*dd*dd);
            dd=pp-muy4.z; Sy[2]+=__expf(2.f*ay4.z*dd*dd);
            dd=pp-muy4.w; Sy[3]+=__expf(2.f*ay4.w*dd*dd);
        }
        sc4.x = sqrtf((float)(HH*WW)/(Sx[0]*Sy[0]));
        sc4.y = sqrtf((float)(HH*WW)/(Sx[1]*Sy[1]));
        sc4.z = sqrtf((float)(HH*WW)/(Sx[2]*Sy[2]));
        sc4.w = sqrtf((float)(HH*WW)/(Sx[3]*Sy[3]));
    }
    __syncthreads();

    float acc[8][4];
#pragma unroll
    for (int b = 0; b < 8; ++b)
        acc[b][0] = acc[b][1] = acc[b][2] = acc[b][3] = 0.f;

#pragma unroll
    for (int rr = 0; rr < 2; ++rr) {
        const int rrow = r0 + rr;
        const int hh = rrow & (HH - 1);
        float4 gys;
        {
            float hp = hh * STEP, dd;
            dd=hp-muy4.x; gys.x = __expf(ay4.x*dd*dd) * sc4.x;
            dd=hp-muy4.y; gys.y = __expf(ay4.y*dd*dd) * sc4.y;
            dd=hp-muy4.z; gys.z = __expf(ay4.z*dd*dd) * sc4.z;
            dd=hp-muy4.w; gys.w = __expf(ay4.w*dd*dd) * sc4.w;
        }
        const float4* wp = (const float4*)(weights + (size_t)rrow * WW * NN) + tid;
        float racc[8][4];
#pragma unroll
        for (int b = 0; b < 8; ++b)
            racc[b][0] = racc[b][1] = racc[b][2] = racc[b][3] = 0.f;
        for (int w = 0; w < WW; ++w) {
            const float4 wt = wp[(size_t)w * (NN/4)];
            float pp = w * STEP, dd;
            float4 t;
            dd=pp-mux4.x; t.x = __expf(ax4.x*dd*dd) * wt.x;
            dd=pp-mux4.y; t.y = __expf(ax4.y*dd*dd) * wt.y;
            dd=pp-mux4.z; t.z = __expf(ax4.z*dd*dd) * wt.z;
            dd=pp-mux4.w; t.w = __expf(ax4.w*dd*dd) * wt.w;
            const float4* trp = (const float4*)&tile[rr][w][0];
            float xs[8];
            ((float4*)xs)[0] = trp[0]; ((float4*)xs)[1] = trp[1];
#pragma unroll
            for (int b = 0; b < 8; ++b) {
                racc[b][0] = fmaf(xs[b], t.x, racc[b][0]);
                racc[b][1] = fmaf(xs[b], t.y, racc[b][1]);
                racc[b][2] = fmaf(xs[b], t.z, racc[b][2]);
                racc[b][3] = fmaf(xs[b], t.w, racc[b][3]);
            }
        }
#pragma unroll
        for (int b = 0; b < 8; ++b) {
            acc[b][0] = fmaf(gys.x, racc[b][0], acc[b][0]);
            acc[b][1] = fmaf(gys.y, racc[b][1], acc[b][1]);
            acc[b][2] = fmaf(gys.z, racc[b][2], acc[b][2]);
            acc[b][3] = fmaf(gys.w, racc[b][3], acc[b][3]);
        }
    }

    float* op = dst + (size_t)b0 * NN + tid * 4;
#pragma unroll
    for (int b = 0; b < 8; ++b) {
        atomicAdd(op + (size_t)b * NN + 0, acc[b][0]);
        atomicAdd(op + (size_t)b * NN + 1, acc[b][1]);
        atomicAdd(op + (size_t)b * NN + 2, acc[b][2]);
        atomicAdd(op + (size_t)b * NN + 3, acc[b][3]);
    }
}

extern "C" void kernel_launch(void* const* d_in, const int* in_sizes, int n_in,
                              void* d_out, int out_size, void* d_ws, size_t ws_size,
                              hipStream_t stream) {
    const float* x       = (const float*)d_in[0];
    const float* mu_x    = (const float*)d_in[1];
    const float* mu_y    = (const float*)d_in[2];
    const float* sigma_x = (const float*)d_in[3];
    const float* sigma_y = (const float*)d_in[4];
    const float* weights = (const float*)d_in[5];
    float* out = (float*)d_out;

    float* scale = (float*)d_ws;                          // 4 KB
    float* xT    = (float*)((char*)d_ws + 4096);          // 6.3 MB
    float* part  = xT + (size_t)KK * BB;                  // 50.3 MB
    float* part2 = part + (size_t)KSR * BB * NN;          // 1 MB
    const size_t need = 4096 +
        sizeof(float) * ((size_t)KK * BB + (size_t)KSR * BB * NN + (size_t)SG * BB * NN);

    if (ws_size >= need) {
        scale_kernel<<<(NN + 255) / 256, 256, 0, stream>>>(mu_x, mu_y, sigma_x, sigma_y, scale);
        xpose_kernel<<<KK / 64, 256, 0, stream>>>(x, xT);
        main_pipe<<<KSR * 4, 256, 0, stream>>>(weights, xT, scale,
                                               mu_x, mu_y, sigma_x, sigma_y, part);
        reduce1_kernel<<<32 * SG, 256, 0, stream>>>(part, part2);
        reduce2_kernel<<<BB * NN / 4 / 256, 256, 0, stream>>>(part2, out);
    } else {
        hipMemsetAsync(d_out, 0, (size_t)out_size * sizeof(float), stream);
        dim3 grid(NROWS / 2, 4);
        main_fallback<<<grid, 256, 0, stream>>>(weights, x,
                                                mu_x, mu_y, sigma_x, sigma_y, out);
    }
}